// Round 2
// baseline (552.987 us; speedup 1.0000x reference)
//
#include <hip/hip_runtime.h>

typedef _Float16 f16;
typedef _Float16 f16x8 __attribute__((ext_vector_type(8)));
typedef _Float16 f16x4 __attribute__((ext_vector_type(4)));
typedef float f32x4 __attribute__((ext_vector_type(4)));

constexpr int HDIM = 256, WDIM = 256, C_ = 192, NH_ = 6;
constexpr float SCALE = 0.17677669529663687f;  // 32^-0.5

// workspace: wq f16 (576x192), wp f16 (192x192)
constexpr size_t OFF_WQ = 0;        // 221184 B
constexpr size_t OFF_WP = 221184;   // 73728 B

__global__ __launch_bounds__(256) void prep_weights(const float* __restrict__ qkv_w,
                                                    const float* __restrict__ proj_w,
                                                    f16* __restrict__ wq, f16* __restrict__ wp) {
    int i = blockIdx.x * 256 + threadIdx.x;
    if (i < 576 * 192) wq[i] = (f16)qkv_w[i];
    if (i < 192 * 192) wp[i] = (f16)proj_w[i];
}

// Fully fused window attention: 1 block = 1 window (64 tokens), 6 waves = 6 heads.
// LDS per head h (all XOR-swizzled, no padding):
//   Rq: q[t][d]  64x32 f16 (later: att output of head h)
//   Rk: k[t][d]  64x32 f16 (later: P halves)
//   Rv: vt[d][t] 32x64 f16
__global__ __launch_bounds__(384) void fused_kernel(const float* __restrict__ x,
                                                    const f16* __restrict__ wq,
                                                    const f16* __restrict__ wp,
                                                    const float* __restrict__ pb,
                                                    const float* __restrict__ rpb,
                                                    float* __restrict__ out) {
    __shared__ f16 smem[6 * 3 * 2048];   // 73728 B
    const int tid = threadIdx.x;
    const int w = tid >> 6;              // wave id == head id
    const int lane = tid & 63;
    const int l15 = lane & 15, lg = lane >> 4;
    const int win = blockIdx.x;
    const int b = win >> 10, wy = (win >> 5) & 31, wx = win & 31;

    f16* Rq = smem + w * 6144;
    f16* Rk = Rq + 2048;
    f16* Rv = Rq + 4096;

    // ---------------- QKV (head w's 96 output cols) ----------------
    // A fragments: x rows (fp32 -> f16), token t = tt*16 + l15, k-chunk lg*8 within ks*32
    f16x8 A[4][6];
#pragma unroll
    for (int tt = 0; tt < 4; ++tt) {
        const int gy = wy * 8 + tt * 2 + (l15 >> 3);
        const int gx = wx * 8 + (l15 & 7);
        const float* xr = x + ((size_t)((b * HDIM + gy) * WDIM + gx)) * C_;
#pragma unroll
        for (int ks = 0; ks < 6; ++ks) {
            const float4* p = (const float4*)(xr + ks * 32 + lg * 8);
            float4 u0 = p[0], u1 = p[1];
            f16x8 a;
            a[0] = (f16)u0.x; a[1] = (f16)u0.y; a[2] = (f16)u0.z; a[3] = (f16)u0.w;
            a[4] = (f16)u1.x; a[5] = (f16)u1.y; a[6] = (f16)u1.z; a[7] = (f16)u1.w;
            A[tt][ks] = a;
        }
    }

#pragma unroll
    for (int ct = 0; ct < 6; ++ct) {     // {q0,q1,k0,k1,v0,v1} 16-col tiles of head w
        const int row0 = (ct >> 1) * 192 + w * 32 + (ct & 1) * 16;
        f16x8 Bf[6];
#pragma unroll
        for (int ks = 0; ks < 6; ++ks)
            Bf[ks] = *((const f16x8*)(wq + (size_t)(row0 + l15) * 192 + ks * 32 + lg * 8));
        f32x4 acc[4];
#pragma unroll
        for (int tt = 0; tt < 4; ++tt) { f32x4 z = {0.f,0.f,0.f,0.f}; acc[tt] = z; }
#pragma unroll
        for (int tt = 0; tt < 4; ++tt)
#pragma unroll
            for (int ks = 0; ks < 6; ++ks)
                acc[tt] = __builtin_amdgcn_mfma_f32_16x16x32_f16(A[tt][ks], Bf[ks], acc[tt], 0, 0, 0);

        if (ct < 4) {
            f16* R = (ct < 2) ? Rq : Rk;
            const int dl = (ct & 1) * 16 + l15;
#pragma unroll
            for (int tt = 0; tt < 4; ++tt)
#pragma unroll
                for (int i = 0; i < 4; ++i) {
                    int t = tt * 16 + lg * 4 + i;
                    R[t * 32 + (((dl >> 3) ^ (t & 3)) << 3) + (dl & 7)] = (f16)acc[tt][i];
                }
        } else {
            const int d = (ct & 1) * 16 + l15;
#pragma unroll
            for (int tt = 0; tt < 4; ++tt) {
                f16x4 vv;
#pragma unroll
                for (int i = 0; i < 4; ++i) vv[i] = (f16)acc[tt][i];
                int u = (tt * 4 + lg) ^ ((d & 7) << 1);
                *((f16x4*)(Rv + d * 64 + u * 4)) = vv;   // vt[d][tokens tt*16+lg*4 .. +3]
            }
        }
    }

    asm volatile("s_waitcnt lgkmcnt(0)" ::: "memory");   // own q/k/vt stores visible

    // ---------------- attention (head w), wave-private ----------------
    f16x8 qf[4], kf[4];
#pragma unroll
    for (int t4 = 0; t4 < 4; ++t4) {
        int t = t4 * 16 + l15;
        int sl = ((lg ^ (l15 & 3)) << 3);
        qf[t4] = *((const f16x8*)(Rq + t * 32 + sl));
        kf[t4] = *((const f16x8*)(Rk + t * 32 + sl));
    }
    // vt fragments (Rv never overwritten)
    f16x8 vf[2][2];
#pragma unroll
    for (int dt = 0; dt < 2; ++dt)
#pragma unroll
        for (int h = 0; h < 2; ++h) {
            int d = dt * 16 + l15;
            int u0 = (h * 8 + lg * 2) ^ ((d & 7) << 1);
            vf[dt][h] = *((const f16x8*)(Rv + d * 64 + u0 * 4));
        }

    f32x4 s[4][4];
#pragma unroll
    for (int qt = 0; qt < 4; ++qt)
#pragma unroll
        for (int kt = 0; kt < 4; ++kt) {
            f32x4 z = {0.f, 0.f, 0.f, 0.f};
            s[qt][kt] = __builtin_amdgcn_mfma_f32_16x16x32_f16(qf[qt], kf[kt], z, 0, 0, 0);
        }

    // scale + relative position bias
#pragma unroll
    for (int qt = 0; qt < 4; ++qt)
#pragma unroll
        for (int kt = 0; kt < 4; ++kt)
#pragma unroll
            for (int i = 0; i < 4; ++i) {
                int q = qt * 16 + lg * 4 + i;
                int kk = kt * 16 + l15;
                int dy = (q >> 3) - (kk >> 3) + 7;
                int dx = (q & 7) - (kk & 7) + 7;
                s[qt][kt][i] = s[qt][kt][i] * SCALE + rpb[(dy * 15 + dx) * NH_ + w];
            }

    // fp32 softmax (row q spread over 16 lanes l15 x 4 kt regs); normalized exp back into s
#pragma unroll
    for (int qt = 0; qt < 4; ++qt)
#pragma unroll
        for (int i = 0; i < 4; ++i) {
            float m = fmaxf(fmaxf(s[qt][0][i], s[qt][1][i]), fmaxf(s[qt][2][i], s[qt][3][i]));
            m = fmaxf(m, __shfl_xor(m, 1));
            m = fmaxf(m, __shfl_xor(m, 2));
            m = fmaxf(m, __shfl_xor(m, 4));
            m = fmaxf(m, __shfl_xor(m, 8));
            float e0 = __expf(s[qt][0][i] - m);
            float e1 = __expf(s[qt][1][i] - m);
            float e2 = __expf(s[qt][2][i] - m);
            float e3 = __expf(s[qt][3][i] - m);
            float sum = e0 + e1 + e2 + e3;
            sum += __shfl_xor(sum, 1);
            sum += __shfl_xor(sum, 2);
            sum += __shfl_xor(sum, 4);
            sum += __shfl_xor(sum, 8);
            float r = 1.0f / sum;
            s[qt][0][i] = e0 * r; s[qt][1][i] = e1 * r;
            s[qt][2][i] = e2 * r; s[qt][3][i] = e3 * r;
        }

    // PV in two k-halves; P transposed through dead k region (wave-private)
    f32x4 o[4][2];
#pragma unroll
    for (int qt = 0; qt < 4; ++qt)
#pragma unroll
        for (int dt = 0; dt < 2; ++dt) { f32x4 z = {0.f,0.f,0.f,0.f}; o[qt][dt] = z; }

#pragma unroll
    for (int h = 0; h < 2; ++h) {
#pragma unroll
        for (int qt = 0; qt < 4; ++qt)
#pragma unroll
            for (int kh = 0; kh < 2; ++kh) {
                int kl = kh * 16 + l15;
#pragma unroll
                for (int i = 0; i < 4; ++i) {
                    int q = qt * 16 + lg * 4 + i;
                    Rk[q * 32 + (((kl >> 3) ^ (q & 3)) << 3) + (kl & 7)] = (f16)s[qt][h * 2 + kh][i];
                }
            }
        asm volatile("s_waitcnt lgkmcnt(0)" ::: "memory");   // P half visible
#pragma unroll
        for (int qt = 0; qt < 4; ++qt) {
            int qrow = qt * 16 + l15;
            f16x8 pa = *((const f16x8*)(Rk + qrow * 32 + ((lg ^ (l15 & 3)) << 3)));
            o[qt][0] = __builtin_amdgcn_mfma_f32_16x16x32_f16(pa, vf[0][h], o[qt][0], 0, 0, 0);
            o[qt][1] = __builtin_amdgcn_mfma_f32_16x16x32_f16(pa, vf[1][h], o[qt][1], 0, 0, 0);
        }
        asm volatile("s_waitcnt lgkmcnt(0)" ::: "memory");   // pa reads done before next half's stores
    }

    // att (head w) -> Rq (q dead, wave-private)
#pragma unroll
    for (int qt = 0; qt < 4; ++qt)
#pragma unroll
        for (int dt = 0; dt < 2; ++dt)
#pragma unroll
            for (int i = 0; i < 4; ++i) {
                int t = qt * 16 + lg * 4 + i;
                int d = dt * 16 + l15;
                Rq[t * 32 + (((d >> 3) ^ (t & 3)) << 3) + (d & 7)] = (f16)o[qt][dt][i];
            }

    __syncthreads();   // all heads' att visible to all waves

    // ---------------- proj (head w -> out cols w*32..w*32+31) ----------------
    f16x8 Ap[4][6];
#pragma unroll
    for (int tt = 0; tt < 4; ++tt) {
        int t = tt * 16 + l15;
        int sl = ((lg ^ (l15 & 3)) << 3);
#pragma unroll
        for (int ks = 0; ks < 6; ++ks)     // k-chunk ks == head ks's att region
            Ap[tt][ks] = *((const f16x8*)(smem + ks * 6144 + t * 32 + sl));
    }

#pragma unroll
    for (int ct = 0; ct < 2; ++ct) {
        const int col0 = w * 32 + ct * 16;
        f16x8 Bp[6];
#pragma unroll
        for (int ks = 0; ks < 6; ++ks)
            Bp[ks] = *((const f16x8*)(wp + (size_t)(col0 + l15) * 192 + ks * 32 + lg * 8));
        f32x4 acc[4];
#pragma unroll
        for (int tt = 0; tt < 4; ++tt) { f32x4 z = {0.f,0.f,0.f,0.f}; acc[tt] = z; }
#pragma unroll
        for (int tt = 0; tt < 4; ++tt)
#pragma unroll
            for (int ks = 0; ks < 6; ++ks)
                acc[tt] = __builtin_amdgcn_mfma_f32_16x16x32_f16(Ap[tt][ks], Bp[ks], acc[tt], 0, 0, 0);

        const float bias = pb[col0 + l15];
#pragma unroll
        for (int tt = 0; tt < 4; ++tt)
#pragma unroll
            for (int i = 0; i < 4; ++i) {
                int t = tt * 16 + lg * 4 + i;
                int gy = wy * 8 + (t >> 3), gx = wx * 8 + (t & 7);
                out[((size_t)((b * HDIM + gy) * WDIM + gx)) * C_ + col0 + l15] = acc[tt][i] + bias;
            }
    }
}

extern "C" void kernel_launch(void* const* d_in, const int* in_sizes, int n_in,
                              void* d_out, int out_size, void* d_ws, size_t ws_size,
                              hipStream_t stream) {
    const float* x      = (const float*)d_in[0];
    const float* qkv_w  = (const float*)d_in[1];
    const float* proj_w = (const float*)d_in[2];
    const float* proj_b = (const float*)d_in[3];
    const float* rpb    = (const float*)d_in[4];
    float* out = (float*)d_out;
    char* ws = (char*)d_ws;
    f16* wq = (f16*)(ws + OFF_WQ);
    f16* wp = (f16*)(ws + OFF_WP);

    prep_weights<<<432, 256, 0, stream>>>(qkv_w, proj_w, wq, wp);
    fused_kernel<<<4096, 384, 0, stream>>>(x, wq, wp, proj_b, rpb, out);
}

// Round 3
// 345.394 us; speedup vs baseline: 1.6010x; 1.6010x over previous
//
#include <hip/hip_runtime.h>

typedef _Float16 f16;
typedef _Float16 f16x8 __attribute__((ext_vector_type(8)));
typedef _Float16 f16x4 __attribute__((ext_vector_type(4)));
typedef float f32x4 __attribute__((ext_vector_type(4)));

constexpr int HDIM = 256, WDIM = 256, C_ = 192, NH_ = 6;
constexpr float SCALE = 0.17677669529663687f;  // 32^-0.5

// workspace layout (bytes)
constexpr size_t OFF_WQ   = 0;         // 576*192 f16 = 221184
constexpr size_t OFF_WP   = 221184;    // 192*192 f16 = 73728
constexpr size_t OFF_BIAS = 294912;    // 6*64*64 f32 = 98304  (bias[h][q][k])
constexpr size_t OFF_ATT  = 393216;    // 4096*64*192 f16 = 100663296

__global__ __launch_bounds__(256) void prep_kernel(const float* __restrict__ qkv_w,
                                                   const float* __restrict__ proj_w,
                                                   const float* __restrict__ rpb,
                                                   f16* __restrict__ wq, f16* __restrict__ wp,
                                                   float* __restrict__ biasT) {
    int i = blockIdx.x * 256 + threadIdx.x;
    if (i < 576 * 192) wq[i] = (f16)qkv_w[i];
    if (i < 192 * 192) wp[i] = (f16)proj_w[i];
    if (i < 6 * 64 * 64) {
        int h = i >> 12, q = (i >> 6) & 63, k = i & 63;
        int dy = (q >> 3) - (k >> 3) + 7;
        int dx = (q & 7) - (k & 7) + 7;
        biasT[i] = rpb[(dy * 15 + dx) * NH_ + h];
    }
}

// ---------- fused QKV + attention: 1 block = 1 window, 6 waves = 6 heads ----------
// x staged once in LDS (f16, frag-contiguous units). q,k computed operand-swapped
// (C[d][t]), v normal (C[t][d]); attention uses 16x16x16 MFMA whose operand layouts
// match those C layouts exactly -> zero transposes. O computed transposed (O^T=V^T P^T)
// so att stores are f16x4.
__global__ __launch_bounds__(384, 2) void qkv_attn_kernel(const float* __restrict__ x,
                                                          const f16* __restrict__ wq,
                                                          const float* __restrict__ biasT,
                                                          f16* __restrict__ att) {
    __shared__ f16 xlds[64 * 192];   // 24576 B, unit u=((tt*6+ks)*4+lg)*16+l15, 8 f16 each
    const int tid = threadIdx.x;
    const int w = tid >> 6;          // wave id == head id
    const int lane = tid & 63;
    const int l15 = lane & 15, lg = lane >> 4;
    const int win = blockIdx.x;
    const int b = win >> 10, wy = (win >> 5) & 31, wx = win & 31;

    // ---- stage x -> LDS (fp32 -> f16), 384 threads: row = tid/6, 32-col part = tid%6
    {
        const int row = tid / 6, part = tid - row * 6;
        const int gy = wy * 8 + (row >> 3), gx = wx * 8 + (row & 7);
        const float* xr = x + ((size_t)((b * HDIM + gy) * WDIM + gx)) * C_ + part * 32;
        const int tt = row >> 4, r15 = row & 15;
#pragma unroll
        for (int c4 = 0; c4 < 4; ++c4) {
            float4 u0 = ((const float4*)xr)[c4 * 2];
            float4 u1 = ((const float4*)xr)[c4 * 2 + 1];
            f16x8 v;
            v[0] = (f16)u0.x; v[1] = (f16)u0.y; v[2] = (f16)u0.z; v[3] = (f16)u0.w;
            v[4] = (f16)u1.x; v[5] = (f16)u1.y; v[6] = (f16)u1.z; v[7] = (f16)u1.w;
            *((f16x8*)(xlds + ((tt * 6 + part) * 4 + c4) * 128 + r15 * 8)) = v;
        }
    }
    __syncthreads();

    // ---- QKV for head w: q,k swapped (A=W rows, B=x), v normal (A=x, B=Wv rows)
    f32x4 aq[2][4], ak[2][4], av[4][2];
#pragma unroll
    for (int i = 0; i < 4; ++i)
#pragma unroll
        for (int j = 0; j < 2; ++j) {
            f32x4 z = {0.f, 0.f, 0.f, 0.f};
            aq[j][i] = z; ak[j][i] = z; av[i][j] = z;
        }

    const int voff = l15 * 192 + lg * 8;   // per-lane f16 offset within a row-block
#pragma unroll
    for (int ks = 0; ks < 6; ++ks) {
        f16x8 Wq[2], Wk[2], Wv[2];
#pragma unroll
        for (int dt = 0; dt < 2; ++dt) {
            Wq[dt] = *((const f16x8*)(wq + (size_t)(      w * 32 + dt * 16) * 192 + ks * 32 + voff));
            Wk[dt] = *((const f16x8*)(wq + (size_t)(192 + w * 32 + dt * 16) * 192 + ks * 32 + voff));
            Wv[dt] = *((const f16x8*)(wq + (size_t)(384 + w * 32 + dt * 16) * 192 + ks * 32 + voff));
        }
#pragma unroll
        for (int tt = 0; tt < 4; ++tt) {
            f16x8 xt = *((const f16x8*)(xlds + ((tt * 6 + ks) * 4 + lg) * 128 + l15 * 8));
            aq[0][tt] = __builtin_amdgcn_mfma_f32_16x16x32_f16(Wq[0], xt, aq[0][tt], 0, 0, 0);
            aq[1][tt] = __builtin_amdgcn_mfma_f32_16x16x32_f16(Wq[1], xt, aq[1][tt], 0, 0, 0);
            ak[0][tt] = __builtin_amdgcn_mfma_f32_16x16x32_f16(Wk[0], xt, ak[0][tt], 0, 0, 0);
            ak[1][tt] = __builtin_amdgcn_mfma_f32_16x16x32_f16(Wk[1], xt, ak[1][tt], 0, 0, 0);
            av[tt][0] = __builtin_amdgcn_mfma_f32_16x16x32_f16(xt, Wv[0], av[tt][0], 0, 0, 0);
            av[tt][1] = __builtin_amdgcn_mfma_f32_16x16x32_f16(xt, Wv[1], av[tt][1], 0, 0, 0);
        }
    }

    // convert to f16 fragments (these ARE 16x16x16 operand layouts)
    // qf/kf[dt][tt]: lane l15 = token, elems = d = dt*16+lg*4+i   (A/B frags, k-dim=d)
    // vf[tt][dt]:    lane l15 = d,     elems = token = tt*16+lg*4+i (A/B frags, k-dim=t)
    f16x4 qf[2][4], kf[2][4], vf[4][2];
#pragma unroll
    for (int dt = 0; dt < 2; ++dt)
#pragma unroll
        for (int tt = 0; tt < 4; ++tt) {
#pragma unroll
            for (int i = 0; i < 4; ++i) {
                qf[dt][tt][i] = (f16)(aq[dt][tt][i] * SCALE);
                kf[dt][tt][i] = (f16)(ak[dt][tt][i]);
                vf[tt][dt][i] = (f16)(av[tt][dt][i]);
            }
        }

    // ---- attention, fully in-register. S^T = K Q^T  (lane l15 = q, regs/lg = k)
    f32x4 oT[2][4];   // [dt][qt], lane l15 = d, elems = q = qt*16+lg*4+i ... (O^T: l15=q? see below)
    float rq[4];
    const float* bq = biasT + w * 4096;
#pragma unroll
    for (int qt = 0; qt < 4; ++qt) {
        f32x4 s[4];
#pragma unroll
        for (int kt = 0; kt < 4; ++kt) {
            f32x4 z = {0.f, 0.f, 0.f, 0.f};
            s[kt] = __builtin_amdgcn_mfma_f32_16x16x16f16(kf[0][kt], qf[0][qt], z, 0, 0, 0);
            s[kt] = __builtin_amdgcn_mfma_f32_16x16x16f16(kf[1][kt], qf[1][qt], s[kt], 0, 0, 0);
        }
        // bias[h][q][k]: lane l15 = q, float4 over k = kt*16+lg*4..+3
#pragma unroll
        for (int kt = 0; kt < 4; ++kt) {
            f32x4 bb = *((const f32x4*)(bq + (qt * 16 + l15) * 64 + kt * 16 + lg * 4));
            s[kt] += bb;
        }
        float m = s[0][0];
#pragma unroll
        for (int kt = 0; kt < 4; ++kt)
#pragma unroll
            for (int i = 0; i < 4; ++i) m = fmaxf(m, s[kt][i]);
        m = fmaxf(m, __shfl_xor(m, 16));
        m = fmaxf(m, __shfl_xor(m, 32));
        float sum = 0.f;
        f16x4 pa[4];
#pragma unroll
        for (int kt = 0; kt < 4; ++kt)
#pragma unroll
            for (int i = 0; i < 4; ++i) {
                float e = __expf(s[kt][i] - m);
                sum += e;
                pa[kt][i] = (f16)e;
            }
        sum += __shfl_xor(sum, 16);
        sum += __shfl_xor(sum, 32);
        rq[qt] = 1.0f / sum;
        // O^T tile: A = V^T (vf: l15 = d-row, k = token), B = P^T (pa: l15 = q-col, k = token)
#pragma unroll
        for (int dt = 0; dt < 2; ++dt) {
            f32x4 z = {0.f, 0.f, 0.f, 0.f};
            f32x4 o = z;
#pragma unroll
            for (int kt = 0; kt < 4; ++kt)
                o = __builtin_amdgcn_mfma_f32_16x16x16f16(vf[kt][dt], pa[kt], o, 0, 0, 0);
            oT[dt][qt] = o;
        }
    }

    // ---- store att (O^T: lane l15 = q-col, rows = d = lg*4+i) -> att[t][c], f16x4
#pragma unroll
    for (int qt = 0; qt < 4; ++qt)
#pragma unroll
        for (int dt = 0; dt < 2; ++dt) {
            f16x4 ov;
#pragma unroll
            for (int i = 0; i < 4; ++i) ov[i] = (f16)(oT[dt][qt][i] * rq[qt]);
            *((f16x4*)(att + (size_t)(win * 64 + qt * 16 + l15) * C_ + w * 32 + dt * 16 + lg * 4)) = ov;
        }
}

// ---------- output projection + un-windowing: 1 block = 2 windows, 4 waves ----------
__global__ __launch_bounds__(256) void proj_kernel(const f16* __restrict__ att,
                                                   const f16* __restrict__ wp,
                                                   const float* __restrict__ pb,
                                                   float* __restrict__ out) {
    const int tid = threadIdx.x;
    const int wv = tid >> 6;
    const int lane = tid & 63;
    const int l15 = lane & 15, lg = lane >> 4;
    const int sb = blockIdx.x;   // 2 windows per block

    f16x8 A[2][6];
#pragma unroll
    for (int a = 0; a < 2; ++a) {
        const int gt = wv * 2 + a;                 // 0..7 over 128 tokens
        const int win = sb * 2 + (gt >> 2);
        const int lt = gt & 3;
        const f16* ar = att + (size_t)(win * 64 + lt * 16 + l15) * C_;
#pragma unroll
        for (int ks = 0; ks < 6; ++ks)
            A[a][ks] = *((const f16x8*)(ar + ks * 32 + lg * 8));
    }

#pragma unroll
    for (int nt = 0; nt < 12; ++nt) {
        f16x8 Bf[6];
#pragma unroll
        for (int ks = 0; ks < 6; ++ks)
            Bf[ks] = *((const f16x8*)(wp + (size_t)(nt * 16 + l15) * 192 + ks * 32 + lg * 8));
        f32x4 acc[2];
#pragma unroll
        for (int a = 0; a < 2; ++a) { f32x4 z = {0.f,0.f,0.f,0.f}; acc[a] = z; }
#pragma unroll
        for (int a = 0; a < 2; ++a)
#pragma unroll
            for (int ks = 0; ks < 6; ++ks)
                acc[a] = __builtin_amdgcn_mfma_f32_16x16x32_f16(A[a][ks], Bf[ks], acc[a], 0, 0, 0);

        const float bias = pb[nt * 16 + l15];
#pragma unroll
        for (int a = 0; a < 2; ++a) {
            const int gt = wv * 2 + a;
            const int win = sb * 2 + (gt >> 2);
            const int lt = gt & 3;
            const int b = win >> 10, wy = (win >> 5) & 31, wx = win & 31;
#pragma unroll
            for (int i = 0; i < 4; ++i) {
                int t = lt * 16 + lg * 4 + i;
                int gy = wy * 8 + (t >> 3), gx = wx * 8 + (t & 7);
                out[((size_t)((b * HDIM + gy) * WDIM + gx)) * C_ + nt * 16 + l15] = acc[a][i] + bias;
            }
        }
    }
}

extern "C" void kernel_launch(void* const* d_in, const int* in_sizes, int n_in,
                              void* d_out, int out_size, void* d_ws, size_t ws_size,
                              hipStream_t stream) {
    const float* x      = (const float*)d_in[0];
    const float* qkv_w  = (const float*)d_in[1];
    const float* proj_w = (const float*)d_in[2];
    const float* proj_b = (const float*)d_in[3];
    const float* rpb    = (const float*)d_in[4];
    float* out = (float*)d_out;
    char* ws = (char*)d_ws;
    f16* wq     = (f16*)(ws + OFF_WQ);
    f16* wp     = (f16*)(ws + OFF_WP);
    float* biasT = (float*)(ws + OFF_BIAS);
    f16* att    = (f16*)(ws + OFF_ATT);

    prep_kernel<<<432, 256, 0, stream>>>(qkv_w, proj_w, rpb, wq, wp, biasT);
    qkv_attn_kernel<<<4096, 384, 0, stream>>>(x, wq, biasT, att);
    proj_kernel<<<2048, 256, 0, stream>>>(att, wp, proj_b, out);
}

// Round 5
// 317.033 us; speedup vs baseline: 1.7443x; 1.0895x over previous
//
#include <hip/hip_runtime.h>

typedef _Float16 f16;
typedef _Float16 f16x8 __attribute__((ext_vector_type(8)));
typedef _Float16 f16x4 __attribute__((ext_vector_type(4)));
typedef __fp16 h16x2 __attribute__((ext_vector_type(2)));
typedef float f32x4 __attribute__((ext_vector_type(4)));

constexpr int HDIM = 256, WDIM = 256, C_ = 192, NH_ = 6;
constexpr float SCALE = 0.17677669529663687f;  // 32^-0.5
constexpr int XP = 200;                        // padded f16 row stride (400B: 2-way banks = free)

// workspace layout (bytes)
constexpr size_t OFF_WQ   = 0;         // 576*192 f16 = 221184
constexpr size_t OFF_WP   = 221184;    // 192*192 f16 = 73728
constexpr size_t OFF_BIAS = 294912;    // 6*64*64 f32 = 98304  (bias[h][q][k])

__global__ __launch_bounds__(256) void prep_kernel(const float* __restrict__ qkv_w,
                                                   const float* __restrict__ proj_w,
                                                   const float* __restrict__ rpb,
                                                   f16* __restrict__ wq, f16* __restrict__ wp,
                                                   float* __restrict__ biasT) {
    int i = blockIdx.x * 256 + threadIdx.x;
    if (i < 576 * 192) wq[i] = (f16)qkv_w[i];
    if (i < 192 * 192) wp[i] = (f16)proj_w[i];
    if (i < 6 * 64 * 64) {
        int h = i >> 12, q = (i >> 6) & 63, k = i & 63;
        int dy = (q >> 3) - (k >> 3) + 7;
        int dx = (q & 7) - (k & 7) + 7;
        biasT[i] = rpb[(dy * 15 + dx) * NH_ + h];
    }
}

// One block = one window (64 tokens), 6 waves = 6 heads. Everything fused:
//  stage x->LDS (coalesced) | QKV per head (swapped q,k) | in-register attention
//  | O^T -> LDS (reuse x buffer) | proj + un-window store.
__global__ __launch_bounds__(384, 2) void fused_kernel(const float* __restrict__ x,
                                                       const f16* __restrict__ wq,
                                                       const f16* __restrict__ wp,
                                                       const float* __restrict__ pb,
                                                       const float* __restrict__ biasT,
                                                       float* __restrict__ out) {
    __shared__ f16 xlds[64 * XP];   // 25600 B; later reused as att[t][c] buffer
    const int tid = threadIdx.x;
    const int w = tid >> 6;          // wave id == head id
    const int lane = tid & 63;
    const int l15 = lane & 15, lg = lane >> 4;
    const int win = blockIdx.x;
    const int b = win >> 10, wy = (win >> 5) & 31, wx = win & 31;

    // ---- stage x -> LDS, fully coalesced: 3072 float4s, 8 per thread ----
#pragma unroll
    for (int it = 0; it < 8; ++it) {
        int u = tid + it * 384;
        int row = u / 48, c4 = u - row * 48;
        int gy = wy * 8 + (row >> 3), gx = wx * 8 + (row & 7);
        float4 v = *((const float4*)(x + ((size_t)((b * HDIM + gy) * WDIM + gx)) * C_ + c4 * 4));
        h16x2 p0 = __builtin_amdgcn_cvt_pkrtz(v.x, v.y);
        h16x2 p1 = __builtin_amdgcn_cvt_pkrtz(v.z, v.w);
        f16x4 o4;
        o4[0] = (f16)p0[0]; o4[1] = (f16)p0[1]; o4[2] = (f16)p1[0]; o4[3] = (f16)p1[1];
        *((f16x4*)(xlds + row * XP + c4 * 4)) = o4;
    }
    __syncthreads();

    // ---- QKV for head w: q,k operand-swapped (C[d][t]), v normal (C[t][d]) ----
    f32x4 aq[2][4], ak[2][4], av[4][2];
#pragma unroll
    for (int i = 0; i < 4; ++i)
#pragma unroll
        for (int j = 0; j < 2; ++j) {
            f32x4 z = {0.f, 0.f, 0.f, 0.f};
            aq[j][i] = z; ak[j][i] = z; av[i][j] = z;
        }

    const int voff = l15 * 192 + lg * 8;
#pragma unroll
    for (int ks = 0; ks < 6; ++ks) {
        f16x8 Wq[2], Wk[2], Wv[2];
#pragma unroll
        for (int dt = 0; dt < 2; ++dt) {
            Wq[dt] = *((const f16x8*)(wq + (size_t)(      w * 32 + dt * 16) * 192 + ks * 32 + voff));
            Wk[dt] = *((const f16x8*)(wq + (size_t)(192 + w * 32 + dt * 16) * 192 + ks * 32 + voff));
            Wv[dt] = *((const f16x8*)(wq + (size_t)(384 + w * 32 + dt * 16) * 192 + ks * 32 + voff));
        }
#pragma unroll
        for (int tt = 0; tt < 4; ++tt) {
            f16x8 xt = *((const f16x8*)(xlds + (tt * 16 + l15) * XP + ks * 32 + lg * 8));
            aq[0][tt] = __builtin_amdgcn_mfma_f32_16x16x32_f16(Wq[0], xt, aq[0][tt], 0, 0, 0);
            aq[1][tt] = __builtin_amdgcn_mfma_f32_16x16x32_f16(Wq[1], xt, aq[1][tt], 0, 0, 0);
            ak[0][tt] = __builtin_amdgcn_mfma_f32_16x16x32_f16(Wk[0], xt, ak[0][tt], 0, 0, 0);
            ak[1][tt] = __builtin_amdgcn_mfma_f32_16x16x32_f16(Wk[1], xt, ak[1][tt], 0, 0, 0);
            av[tt][0] = __builtin_amdgcn_mfma_f32_16x16x32_f16(xt, Wv[0], av[tt][0], 0, 0, 0);
            av[tt][1] = __builtin_amdgcn_mfma_f32_16x16x32_f16(xt, Wv[1], av[tt][1], 0, 0, 0);
        }
    }
    __syncthreads();   // all waves done reading xlds (buffer becomes att)

    // f16 fragments in 16x16x16 operand layouts
    f16x4 qf[2][4], kf[2][4], vf[4][2];
#pragma unroll
    for (int dt = 0; dt < 2; ++dt)
#pragma unroll
        for (int tt = 0; tt < 4; ++tt)
#pragma unroll
            for (int i = 0; i < 4; ++i) {
                qf[dt][tt][i] = (f16)(aq[dt][tt][i] * SCALE);
                kf[dt][tt][i] = (f16)(ak[dt][tt][i]);
                vf[tt][dt][i] = (f16)(av[tt][dt][i]);
            }

    // ---- attention, fully in-register ----
    const float* bq = biasT + w * 4096;
    f32x4 oT[2][4];
    float rq[4];
#pragma unroll
    for (int qt = 0; qt < 4; ++qt) {
        f32x4 bb[4];
#pragma unroll
        for (int kt = 0; kt < 4; ++kt)
            bb[kt] = *((const f32x4*)(bq + (qt * 16 + l15) * 64 + kt * 16 + lg * 4));
        f32x4 s[4];
#pragma unroll
        for (int kt = 0; kt < 4; ++kt) {
            f32x4 z = {0.f, 0.f, 0.f, 0.f};
            s[kt] = __builtin_amdgcn_mfma_f32_16x16x16f16(kf[0][kt], qf[0][qt], z, 0, 0, 0);
            s[kt] = __builtin_amdgcn_mfma_f32_16x16x16f16(kf[1][kt], qf[1][qt], s[kt], 0, 0, 0);
        }
#pragma unroll
        for (int kt = 0; kt < 4; ++kt) s[kt] += bb[kt];

        float m = s[0][0];
#pragma unroll
        for (int kt = 0; kt < 4; ++kt)
#pragma unroll
            for (int i = 0; i < 4; ++i) m = fmaxf(m, s[kt][i]);
        m = fmaxf(m, __shfl_xor(m, 16));
        m = fmaxf(m, __shfl_xor(m, 32));
        float sum = 0.f;
        f16x4 pa[4];
#pragma unroll
        for (int kt = 0; kt < 4; ++kt)
#pragma unroll
            for (int i = 0; i < 4; ++i) {
                float e = __expf(s[kt][i] - m);
                sum += e;
                pa[kt][i] = (f16)e;
            }
        sum += __shfl_xor(sum, 16);
        sum += __shfl_xor(sum, 32);
        rq[qt] = 1.0f / sum;

        // O^T = V^T P^T, split 2+2 accumulation for ILP
#pragma unroll
        for (int dt = 0; dt < 2; ++dt) {
            f32x4 z = {0.f, 0.f, 0.f, 0.f};
            f32x4 o0 = __builtin_amdgcn_mfma_f32_16x16x16f16(vf[0][dt], pa[0], z, 0, 0, 0);
            o0 = __builtin_amdgcn_mfma_f32_16x16x16f16(vf[1][dt], pa[1], o0, 0, 0, 0);
            f32x4 o1 = __builtin_amdgcn_mfma_f32_16x16x16f16(vf[2][dt], pa[2], z, 0, 0, 0);
            o1 = __builtin_amdgcn_mfma_f32_16x16x16f16(vf[3][dt], pa[3], o1, 0, 0, 0);
            oT[dt][qt] = o0 + o1;
        }
    }

    // ---- O^T (head w) -> att LDS rows [t][c], c = w*32 + dt*16 + lg*4 + i ----
#pragma unroll
    for (int qt = 0; qt < 4; ++qt)
#pragma unroll
        for (int dt = 0; dt < 2; ++dt) {
            f16x4 ov;
#pragma unroll
            for (int i = 0; i < 4; ++i) ov[i] = (f16)(oT[dt][qt][i] * rq[qt]);
            *((f16x4*)(xlds + (qt * 16 + l15) * XP + w * 32 + dt * 16 + lg * 4)) = ov;
        }
    __syncthreads();   // all heads' att visible

    // ---- proj: wave w -> out channels w*32 .. w*32+31 ----
    f16x8 wpf[2][6];
#pragma unroll
    for (int nt = 0; nt < 2; ++nt)
#pragma unroll
        for (int ks = 0; ks < 6; ++ks)
            wpf[nt][ks] = *((const f16x8*)(wp + (size_t)(w * 32 + nt * 16 + l15) * 192 + ks * 32 + lg * 8));
    f32x4 bv[2];
#pragma unroll
    for (int nt = 0; nt < 2; ++nt)
        bv[nt] = *((const f32x4*)(pb + w * 32 + nt * 16 + lg * 4));

#pragma unroll
    for (int qt = 0; qt < 4; ++qt) {
        f16x8 af[6];
#pragma unroll
        for (int ks = 0; ks < 6; ++ks)
            af[ks] = *((const f16x8*)(xlds + (qt * 16 + l15) * XP + ks * 32 + lg * 8));
        const int t = qt * 16 + l15;
        const int gy = wy * 8 + (t >> 3), gx = wx * 8 + (t & 7);
        float* orow = out + ((size_t)((b * HDIM + gy) * WDIM + gx)) * C_ + w * 32;
#pragma unroll
        for (int nt = 0; nt < 2; ++nt) {
            f32x4 acc = {0.f, 0.f, 0.f, 0.f};
#pragma unroll
            for (int ks = 0; ks < 6; ++ks)
                acc = __builtin_amdgcn_mfma_f32_16x16x32_f16(wpf[nt][ks], af[ks], acc, 0, 0, 0);
            acc += bv[nt];
            *((f32x4*)(orow + nt * 16 + lg * 4)) = acc;
        }
    }
}

extern "C" void kernel_launch(void* const* d_in, const int* in_sizes, int n_in,
                              void* d_out, int out_size, void* d_ws, size_t ws_size,
                              hipStream_t stream) {
    const float* x      = (const float*)d_in[0];
    const float* qkv_w  = (const float*)d_in[1];
    const float* proj_w = (const float*)d_in[2];
    const float* proj_b = (const float*)d_in[3];
    const float* rpb    = (const float*)d_in[4];
    float* out = (float*)d_out;
    char* ws = (char*)d_ws;
    f16* wq      = (f16*)(ws + OFF_WQ);
    f16* wp      = (f16*)(ws + OFF_WP);
    float* biasT = (float*)(ws + OFF_BIAS);

    prep_kernel<<<432, 256, 0, stream>>>(qkv_w, proj_w, rpb, wq, wp, biasT);
    fused_kernel<<<4096, 384, 0, stream>>>(x, wq, wp, proj_b, biasT, out);
}

// Round 7
// 214.052 us; speedup vs baseline: 2.5834x; 1.4811x over previous
//
#include <hip/hip_runtime.h>

typedef _Float16 f16;
typedef _Float16 f16x8 __attribute__((ext_vector_type(8)));
typedef _Float16 f16x4 __attribute__((ext_vector_type(4)));
typedef __fp16 h16x2 __attribute__((ext_vector_type(2)));
typedef float f32x4 __attribute__((ext_vector_type(4)));

constexpr int HDIM = 256, WDIM = 256, C_ = 192, NH_ = 6;
constexpr float SCALE = 0.17677669529663687f;  // 32^-0.5
constexpr int XP = 200;                        // padded f16 row stride

// workspace layout (bytes)
constexpr size_t OFF_WQ   = 0;         // packed qkv weights: 6*36*64 frags * 8 f16 = 221184 B
constexpr size_t OFF_WP   = 221184;    // packed proj weights: 6*12*64 frags * 8 f16 = 73728 B
constexpr size_t OFF_BIAS = 294912;    // packed bias: 6*16*64 frags * 4 f32 = 98304 B

// Repack weights & bias into per-wave fragment order so every global load in the
// hot kernel is one coalesced 1KB burst.
//   qkv entries : 6h * 3c * 2dt * 6ks * 64lane = 13824, each 8 f16
//   proj entries: 6h * 2nt * 6ks * 64lane      =  4608, each 8 f16
//   bias entries: 6h * 4qt * 4kt * 64lane      =  6144, each 4 f32
__global__ __launch_bounds__(256) void prep_kernel(const float* __restrict__ qkv_w,
                                                   const float* __restrict__ proj_w,
                                                   const float* __restrict__ rpb,
                                                   f16* __restrict__ wqp, f16* __restrict__ wpp,
                                                   float* __restrict__ biasp) {
    int i = blockIdx.x * 256 + threadIdx.x;
    if (i < 13824) {                       // qkv frags: entry = ((w*3+c)*2+dt)*6+ks
        int lane = i & 63, rest = i >> 6;
        int ks = rest % 6; rest /= 6;
        int dt = rest & 1; rest >>= 1;
        int c = rest % 3, w = rest / 3;
        int l15 = lane & 15, lg = lane >> 4;
        int row = c * 192 + w * 32 + dt * 16 + l15;
        int col = ks * 32 + lg * 8;
#pragma unroll
        for (int j = 0; j < 8; ++j) wqp[(size_t)i * 8 + j] = (f16)qkv_w[row * 192 + col + j];
    } else if (i < 18432) {                // proj frags: entry = (w*2+nt)*6+ks
        int g = i - 13824;
        int lane = g & 63, rest = g >> 6;
        int ks = rest % 6; rest /= 6;
        int nt = rest & 1, w = rest >> 1;
        int l15 = lane & 15, lg = lane >> 4;
        int row = w * 32 + nt * 16 + l15;
        int col = ks * 32 + lg * 8;
#pragma unroll
        for (int j = 0; j < 8; ++j) wpp[(size_t)g * 8 + j] = (f16)proj_w[row * 192 + col + j];
    } else if (i < 24576) {                // bias frags: entry = (h*4+qt)*4+kt
        int g = i - 18432;
        int lane = g & 63;
        int kt = (g >> 6) & 3, qt = (g >> 8) & 3, h = g >> 10;
        int q = qt * 16 + (lane & 15);
#pragma unroll
        for (int j = 0; j < 4; ++j) {
            int k = kt * 16 + (lane >> 4) * 4 + j;
            int dy = (q >> 3) - (k >> 3) + 7;
            int dx = (q & 7) - (k & 7) + 7;
            biasp[(size_t)g * 4 + j] = rpb[(dy * 15 + dx) * NH_ + h];
        }
    }
}

// One block = one window, 6 waves = 6 heads, fully fused.
// Head-w weights pinned in VGPRs (loads issued before x staging -> latency hidden).
__global__ __launch_bounds__(384, 2) void fused_kernel(const float* __restrict__ x,
                                                       const f16* __restrict__ wqp,
                                                       const f16* __restrict__ wpp,
                                                       const float* __restrict__ pb,
                                                       const float* __restrict__ biasp,
                                                       float* __restrict__ out) {
    __shared__ f16 xlds[64 * XP];
    const int tid = threadIdx.x;
    const int w = tid >> 6;
    const int lane = tid & 63;
    const int l15 = lane & 15, lg = lane >> 4;
    const int win = blockIdx.x;
    const int b = win >> 10, wy = (win >> 5) & 31, wx = win & 31;

    // ---- issue ALL of head w's qkv-weight loads first (36 x 1KB coalesced bursts) ----
    const f16x8* wb = (const f16x8*)wqp + (size_t)w * 36 * 64 + lane;
    f16x8 Wq[2][6], Wk[2][6], Wv[2][6];
#pragma unroll
    for (int dt = 0; dt < 2; ++dt)
#pragma unroll
        for (int ks = 0; ks < 6; ++ks) {
            Wq[dt][ks] = wb[(size_t)((0 * 2 + dt) * 6 + ks) * 64];
            Wk[dt][ks] = wb[(size_t)((1 * 2 + dt) * 6 + ks) * 64];
            Wv[dt][ks] = wb[(size_t)((2 * 2 + dt) * 6 + ks) * 64];
        }

    // ---- stage x -> LDS (coalesced float4s), overlaps weight loads ----
#pragma unroll
    for (int it = 0; it < 8; ++it) {
        int u = tid + it * 384;
        int row = u / 48, c4 = u - row * 48;
        int gy = wy * 8 + (row >> 3), gx = wx * 8 + (row & 7);
        float4 v = *((const float4*)(x + ((size_t)((b * HDIM + gy) * WDIM + gx)) * C_ + c4 * 4));
        h16x2 p0 = __builtin_amdgcn_cvt_pkrtz(v.x, v.y);
        h16x2 p1 = __builtin_amdgcn_cvt_pkrtz(v.z, v.w);
        f16x4 o4;
        o4[0] = (f16)p0[0]; o4[1] = (f16)p0[1]; o4[2] = (f16)p1[0]; o4[3] = (f16)p1[1];
        *((f16x4*)(xlds + row * XP + c4 * 4)) = o4;
    }
    __syncthreads();

    // ---- QKV: pure LDS-read + MFMA (weights pinned) ----
    f32x4 aq[2][4], ak[2][4], av[4][2];
#pragma unroll
    for (int i = 0; i < 4; ++i)
#pragma unroll
        for (int j = 0; j < 2; ++j) {
            f32x4 z = {0.f, 0.f, 0.f, 0.f};
            aq[j][i] = z; ak[j][i] = z; av[i][j] = z;
        }
#pragma unroll
    for (int ks = 0; ks < 6; ++ks)
#pragma unroll
        for (int tt = 0; tt < 4; ++tt) {
            f16x8 xt = *((const f16x8*)(xlds + (tt * 16 + l15) * XP + ks * 32 + lg * 8));
            aq[0][tt] = __builtin_amdgcn_mfma_f32_16x16x32_f16(Wq[0][ks], xt, aq[0][tt], 0, 0, 0);
            aq[1][tt] = __builtin_amdgcn_mfma_f32_16x16x32_f16(Wq[1][ks], xt, aq[1][tt], 0, 0, 0);
            ak[0][tt] = __builtin_amdgcn_mfma_f32_16x16x32_f16(Wk[0][ks], xt, ak[0][tt], 0, 0, 0);
            ak[1][tt] = __builtin_amdgcn_mfma_f32_16x16x32_f16(Wk[1][ks], xt, ak[1][tt], 0, 0, 0);
            av[tt][0] = __builtin_amdgcn_mfma_f32_16x16x32_f16(xt, Wv[0][ks], av[tt][0], 0, 0, 0);
            av[tt][1] = __builtin_amdgcn_mfma_f32_16x16x32_f16(xt, Wv[1][ks], av[tt][1], 0, 0, 0);
        }

    // ---- issue bias + proj-weight loads (coalesced bursts), hidden behind barrier ----
    f32x4 bb[4][4];
    {
        const f32x4* bbase = (const f32x4*)biasp + (size_t)w * 16 * 64 + lane;
#pragma unroll
        for (int qt = 0; qt < 4; ++qt)
#pragma unroll
            for (int kt = 0; kt < 4; ++kt)
                bb[qt][kt] = bbase[(size_t)(qt * 4 + kt) * 64];
    }
    f16x8 wpf[2][6];
    {
        const f16x8* pbse = (const f16x8*)wpp + (size_t)w * 12 * 64 + lane;
#pragma unroll
        for (int nt = 0; nt < 2; ++nt)
#pragma unroll
            for (int ks = 0; ks < 6; ++ks)
                wpf[nt][ks] = pbse[(size_t)(nt * 6 + ks) * 64];
    }
    f32x4 bv[2];
#pragma unroll
    for (int nt = 0; nt < 2; ++nt)
        bv[nt] = *((const f32x4*)(pb + w * 32 + nt * 16 + lg * 4));

    __syncthreads();   // all waves done reading xlds (buffer becomes att)

    // f16 fragments in 16x16x16 operand layouts
    f16x4 qf[2][4], kf[2][4], vf[4][2];
#pragma unroll
    for (int dt = 0; dt < 2; ++dt)
#pragma unroll
        for (int tt = 0; tt < 4; ++tt)
#pragma unroll
            for (int i = 0; i < 4; ++i) {
                qf[dt][tt][i] = (f16)(aq[dt][tt][i] * SCALE);
                kf[dt][tt][i] = (f16)(ak[dt][tt][i]);
                vf[tt][dt][i] = (f16)(av[tt][dt][i]);
            }

    // ---- attention, fully in-register ----
    f32x4 oT[2][4];
    float rq[4];
#pragma unroll
    for (int qt = 0; qt < 4; ++qt) {
        f32x4 s[4];
#pragma unroll
        for (int kt = 0; kt < 4; ++kt) {
            f32x4 z = {0.f, 0.f, 0.f, 0.f};
            s[kt] = __builtin_amdgcn_mfma_f32_16x16x16f16(kf[0][kt], qf[0][qt], z, 0, 0, 0);
            s[kt] = __builtin_amdgcn_mfma_f32_16x16x16f16(kf[1][kt], qf[1][qt], s[kt], 0, 0, 0);
        }
#pragma unroll
        for (int kt = 0; kt < 4; ++kt) s[kt] += bb[qt][kt];

        float m = s[0][0];
#pragma unroll
        for (int kt = 0; kt < 4; ++kt)
#pragma unroll
            for (int i = 0; i < 4; ++i) m = fmaxf(m, s[kt][i]);
        m = fmaxf(m, __shfl_xor(m, 16));
        m = fmaxf(m, __shfl_xor(m, 32));
        float sum = 0.f;
        f16x4 pa[4];
#pragma unroll
        for (int kt = 0; kt < 4; ++kt)
#pragma unroll
            for (int i = 0; i < 4; ++i) {
                float e = __expf(s[kt][i] - m);
                sum += e;
                pa[kt][i] = (f16)e;
            }
        sum += __shfl_xor(sum, 16);
        sum += __shfl_xor(sum, 32);
        rq[qt] = 1.0f / sum;

#pragma unroll
        for (int dt = 0; dt < 2; ++dt) {
            f32x4 z = {0.f, 0.f, 0.f, 0.f};
            f32x4 o0 = __builtin_amdgcn_mfma_f32_16x16x16f16(vf[0][dt], pa[0], z, 0, 0, 0);
            o0 = __builtin_amdgcn_mfma_f32_16x16x16f16(vf[1][dt], pa[1], o0, 0, 0, 0);
            f32x4 o1 = __builtin_amdgcn_mfma_f32_16x16x16f16(vf[2][dt], pa[2], z, 0, 0, 0);
            o1 = __builtin_amdgcn_mfma_f32_16x16x16f16(vf[3][dt], pa[3], o1, 0, 0, 0);
            oT[dt][qt] = o0 + o1;
        }
    }

    // ---- O^T (head w) -> att LDS rows [t][c] ----
#pragma unroll
    for (int qt = 0; qt < 4; ++qt)
#pragma unroll
        for (int dt = 0; dt < 2; ++dt) {
            f16x4 ov;
#pragma unroll
            for (int i = 0; i < 4; ++i) ov[i] = (f16)(oT[dt][qt][i] * rq[qt]);
            *((f16x4*)(xlds + (qt * 16 + l15) * XP + w * 32 + dt * 16 + lg * 4)) = ov;
        }
    __syncthreads();   // all heads' att visible

    // ---- proj: wave w -> out channels w*32 .. w*32+31 (weights pinned) ----
#pragma unroll
    for (int qt = 0; qt < 4; ++qt) {
        f16x8 af[6];
#pragma unroll
        for (int ks = 0; ks < 6; ++ks)
            af[ks] = *((const f16x8*)(xlds + (qt * 16 + l15) * XP + ks * 32 + lg * 8));
        const int t = qt * 16 + l15;
        const int gy = wy * 8 + (t >> 3), gx = wx * 8 + (t & 7);
        float* orow = out + ((size_t)((b * HDIM + gy) * WDIM + gx)) * C_ + w * 32;
#pragma unroll
        for (int nt = 0; nt < 2; ++nt) {
            f32x4 acc = {0.f, 0.f, 0.f, 0.f};
#pragma unroll
            for (int ks = 0; ks < 6; ++ks)
                acc = __builtin_amdgcn_mfma_f32_16x16x32_f16(wpf[nt][ks], af[ks], acc, 0, 0, 0);
            acc += bv[nt];
            *((f32x4*)(orow + nt * 16 + lg * 4)) = acc;
        }
    }
}

extern "C" void kernel_launch(void* const* d_in, const int* in_sizes, int n_in,
                              void* d_out, int out_size, void* d_ws, size_t ws_size,
                              hipStream_t stream) {
    const float* x      = (const float*)d_in[0];
    const float* qkv_w  = (const float*)d_in[1];
    const float* proj_w = (const float*)d_in[2];
    const float* proj_b = (const float*)d_in[3];
    const float* rpb    = (const float*)d_in[4];
    float* out = (float*)d_out;
    char* ws = (char*)d_ws;
    f16* wqp     = (f16*)(ws + OFF_WQ);
    f16* wpp     = (f16*)(ws + OFF_WP);
    float* biasp = (float*)(ws + OFF_BIAS);

    prep_kernel<<<96, 256, 0, stream>>>(qkv_w, proj_w, rpb, wqp, wpp, biasp);
    fused_kernel<<<4096, 384, 0, stream>>>(x, wqp, wpp, proj_b, biasp, out);
}

// Round 8
// 199.442 us; speedup vs baseline: 2.7727x; 1.0733x over previous
//
#include <hip/hip_runtime.h>

typedef _Float16 f16;
typedef _Float16 f16x8 __attribute__((ext_vector_type(8)));
typedef _Float16 f16x4 __attribute__((ext_vector_type(4)));
typedef __fp16 h16x2 __attribute__((ext_vector_type(2)));
typedef float f32x4 __attribute__((ext_vector_type(4)));

constexpr int HDIM = 256, WDIM = 256, C_ = 192, NH_ = 6;
constexpr float SCALE = 0.17677669529663687f;  // 32^-0.5
constexpr int XP = 200;                        // padded f16 row stride

#define KEEP(v) asm volatile("" : "+v"(v))

// workspace layout (bytes)
constexpr size_t OFF_WQ   = 0;         // packed qkv weights: 13824 frags * 8 f16 = 221184 B
constexpr size_t OFF_WP   = 221184;    // packed proj weights: 4608 frags * 8 f16 = 73728 B
constexpr size_t OFF_BIAS = 294912;    // packed bias: 6144 frags * 4 f32 = 98304 B

__global__ __launch_bounds__(256) void prep_kernel(const float* __restrict__ qkv_w,
                                                   const float* __restrict__ proj_w,
                                                   const float* __restrict__ rpb,
                                                   f16* __restrict__ wqp, f16* __restrict__ wpp,
                                                   float* __restrict__ biasp) {
    int i = blockIdx.x * 256 + threadIdx.x;
    if (i < 13824) {                       // qkv frags: entry = ((w*3+c)*2+dt)*6+ks
        int lane = i & 63, rest = i >> 6;
        int ks = rest % 6; rest /= 6;
        int dt = rest & 1; rest >>= 1;
        int c = rest % 3, w = rest / 3;
        int l15 = lane & 15, lg = lane >> 4;
        int row = c * 192 + w * 32 + dt * 16 + l15;
        int col = ks * 32 + lg * 8;
#pragma unroll
        for (int j = 0; j < 8; ++j) wqp[(size_t)i * 8 + j] = (f16)qkv_w[row * 192 + col + j];
    } else if (i < 18432) {                // proj frags: entry = (w*2+nt)*6+ks
        int g = i - 13824;
        int lane = g & 63, rest = g >> 6;
        int ks = rest % 6; rest /= 6;
        int nt = rest & 1, w = rest >> 1;
        int l15 = lane & 15, lg = lane >> 4;
        int row = w * 32 + nt * 16 + l15;
        int col = ks * 32 + lg * 8;
#pragma unroll
        for (int j = 0; j < 8; ++j) wpp[(size_t)g * 8 + j] = (f16)proj_w[row * 192 + col + j];
    } else if (i < 24576) {                // bias frags: entry = (h*4+qt)*4+kt
        int g = i - 18432;
        int lane = g & 63;
        int kt = (g >> 6) & 3, qt = (g >> 8) & 3, h = g >> 10;
        int q = qt * 16 + (lane & 15);
#pragma unroll
        for (int j = 0; j < 4; ++j) {
            int k = kt * 16 + (lane >> 4) * 4 + j;
            int dy = (q >> 3) - (k >> 3) + 7;
            int dx = (q & 7) - (k & 7) + 7;
            biasp[(size_t)g * 4 + j] = rpb[(dy * 15 + dx) * NH_ + h];
        }
    }
}

// One block = one window, 6 waves = 6 heads, fully fused.
// Weight fragments force-pinned in VGPRs via keep-alive asm.
__global__ __launch_bounds__(384, 2) void fused_kernel(const float* __restrict__ x,
                                                       const f16* __restrict__ wqp,
                                                       const f16* __restrict__ wpp,
                                                       const float* __restrict__ pb,
                                                       const float* __restrict__ biasp,
                                                       float* __restrict__ out) {
    __shared__ f16 xlds[64 * XP];
    const int tid = threadIdx.x;
    const int w = tid >> 6;
    const int lane = tid & 63;
    const int l15 = lane & 15, lg = lane >> 4;
    const int win = blockIdx.x;
    const int b = win >> 10, wy = (win >> 5) & 31, wx = win & 31;

    // ---- issue ALL of head w's qkv-weight loads first (36 x 1KB coalesced bursts) ----
    const f16x8* wb = (const f16x8*)wqp + (size_t)w * 36 * 64 + lane;
    f16x8 Wq[2][6], Wk[2][6], Wv[2][6];
#pragma unroll
    for (int dt = 0; dt < 2; ++dt)
#pragma unroll
        for (int ks = 0; ks < 6; ++ks) {
            Wq[dt][ks] = wb[(size_t)((0 * 2 + dt) * 6 + ks) * 64];
            Wk[dt][ks] = wb[(size_t)((1 * 2 + dt) * 6 + ks) * 64];
            Wv[dt][ks] = wb[(size_t)((2 * 2 + dt) * 6 + ks) * 64];
        }

    // ---- stage x -> LDS (coalesced float4s), overlaps weight-load latency ----
#pragma unroll
    for (int it = 0; it < 8; ++it) {
        int u = tid + it * 384;
        int row = u / 48, c4 = u - row * 48;
        int gy = wy * 8 + (row >> 3), gx = wx * 8 + (row & 7);
        float4 v = *((const float4*)(x + ((size_t)((b * HDIM + gy) * WDIM + gx)) * C_ + c4 * 4));
        h16x2 p0 = __builtin_amdgcn_cvt_pkrtz(v.x, v.y);
        h16x2 p1 = __builtin_amdgcn_cvt_pkrtz(v.z, v.w);
        f16x4 o4;
        o4[0] = (f16)p0[0]; o4[1] = (f16)p0[1]; o4[2] = (f16)p1[0]; o4[3] = (f16)p1[1];
        *((f16x4*)(xlds + row * XP + c4 * 4)) = o4;
    }

    // force all 36 weight frags resident in VGPRs here (loads complete during staging)
#pragma unroll
    for (int dt = 0; dt < 2; ++dt)
#pragma unroll
        for (int ks = 0; ks < 6; ++ks) {
            KEEP(Wq[dt][ks]); KEEP(Wk[dt][ks]); KEEP(Wv[dt][ks]);
        }
    __syncthreads();

    // ---- QKV: pure LDS-read + MFMA (weights pinned) ----
    f32x4 aq[2][4], ak[2][4], av[4][2];
#pragma unroll
    for (int i = 0; i < 4; ++i)
#pragma unroll
        for (int j = 0; j < 2; ++j) {
            f32x4 z = {0.f, 0.f, 0.f, 0.f};
            aq[j][i] = z; ak[j][i] = z; av[i][j] = z;
        }
#pragma unroll
    for (int ks = 0; ks < 6; ++ks)
#pragma unroll
        for (int tt = 0; tt < 4; ++tt) {
            f16x8 xt = *((const f16x8*)(xlds + (tt * 16 + l15) * XP + ks * 32 + lg * 8));
            aq[0][tt] = __builtin_amdgcn_mfma_f32_16x16x32_f16(Wq[0][ks], xt, aq[0][tt], 0, 0, 0);
            aq[1][tt] = __builtin_amdgcn_mfma_f32_16x16x32_f16(Wq[1][ks], xt, aq[1][tt], 0, 0, 0);
            ak[0][tt] = __builtin_amdgcn_mfma_f32_16x16x32_f16(Wk[0][ks], xt, ak[0][tt], 0, 0, 0);
            ak[1][tt] = __builtin_amdgcn_mfma_f32_16x16x32_f16(Wk[1][ks], xt, ak[1][tt], 0, 0, 0);
            av[tt][0] = __builtin_amdgcn_mfma_f32_16x16x32_f16(xt, Wv[0][ks], av[tt][0], 0, 0, 0);
            av[tt][1] = __builtin_amdgcn_mfma_f32_16x16x32_f16(xt, Wv[1][ks], av[tt][1], 0, 0, 0);
        }

    // ---- issue bias + proj-weight loads (coalesced bursts) ----
    f32x4 bb[4][4];
    {
        const f32x4* bbase = (const f32x4*)biasp + (size_t)w * 16 * 64 + lane;
#pragma unroll
        for (int qt = 0; qt < 4; ++qt)
#pragma unroll
            for (int kt = 0; kt < 4; ++kt)
                bb[qt][kt] = bbase[(size_t)(qt * 4 + kt) * 64];
    }
    f16x8 wpf[2][6];
    {
        const f16x8* pbse = (const f16x8*)wpp + (size_t)w * 12 * 64 + lane;
#pragma unroll
        for (int nt = 0; nt < 2; ++nt)
#pragma unroll
            for (int ks = 0; ks < 6; ++ks)
                wpf[nt][ks] = pbse[(size_t)(nt * 6 + ks) * 64];
    }
    f32x4 bv[2];
#pragma unroll
    for (int nt = 0; nt < 2; ++nt)
        bv[nt] = *((const f32x4*)(pb + w * 32 + nt * 16 + lg * 4));

    __syncthreads();   // all waves done reading xlds (buffer becomes att)

    // f16 fragments in 16x16x16 operand layouts
    f16x4 qf[2][4], kf[2][4], vf[4][2];
#pragma unroll
    for (int dt = 0; dt < 2; ++dt)
#pragma unroll
        for (int tt = 0; tt < 4; ++tt)
#pragma unroll
            for (int i = 0; i < 4; ++i) {
                qf[dt][tt][i] = (f16)(aq[dt][tt][i] * SCALE);
                kf[dt][tt][i] = (f16)(ak[dt][tt][i]);
                vf[tt][dt][i] = (f16)(av[tt][dt][i]);
            }

    // force bias resident before attention (loads completed during QKV)
#pragma unroll
    for (int qt = 0; qt < 4; ++qt)
#pragma unroll
        for (int kt = 0; kt < 4; ++kt) KEEP(bb[qt][kt]);

    // ---- attention, fully in-register ----
    f32x4 oT[2][4];
    float rq[4];
#pragma unroll
    for (int qt = 0; qt < 4; ++qt) {
        f32x4 s[4];
#pragma unroll
        for (int kt = 0; kt < 4; ++kt) {
            f32x4 z = {0.f, 0.f, 0.f, 0.f};
            s[kt] = __builtin_amdgcn_mfma_f32_16x16x16f16(kf[0][kt], qf[0][qt], z, 0, 0, 0);
            s[kt] = __builtin_amdgcn_mfma_f32_16x16x16f16(kf[1][kt], qf[1][qt], s[kt], 0, 0, 0);
        }
#pragma unroll
        for (int kt = 0; kt < 4; ++kt) s[kt] += bb[qt][kt];

        float m = s[0][0];
#pragma unroll
        for (int kt = 0; kt < 4; ++kt)
#pragma unroll
            for (int i = 0; i < 4; ++i) m = fmaxf(m, s[kt][i]);
        m = fmaxf(m, __shfl_xor(m, 16));
        m = fmaxf(m, __shfl_xor(m, 32));
        float sum = 0.f;
        f16x4 pa[4];
#pragma unroll
        for (int kt = 0; kt < 4; ++kt)
#pragma unroll
            for (int i = 0; i < 4; ++i) {
                float e = __expf(s[kt][i] - m);
                sum += e;
                pa[kt][i] = (f16)e;
            }
        sum += __shfl_xor(sum, 16);
        sum += __shfl_xor(sum, 32);
        rq[qt] = 1.0f / sum;

#pragma unroll
        for (int dt = 0; dt < 2; ++dt) {
            f32x4 z = {0.f, 0.f, 0.f, 0.f};
            f32x4 o0 = __builtin_amdgcn_mfma_f32_16x16x16f16(vf[0][dt], pa[0], z, 0, 0, 0);
            o0 = __builtin_amdgcn_mfma_f32_16x16x16f16(vf[1][dt], pa[1], o0, 0, 0, 0);
            f32x4 o1 = __builtin_amdgcn_mfma_f32_16x16x16f16(vf[2][dt], pa[2], z, 0, 0, 0);
            o1 = __builtin_amdgcn_mfma_f32_16x16x16f16(vf[3][dt], pa[3], o1, 0, 0, 0);
            oT[dt][qt] = o0 + o1;
        }
    }

    // ---- O^T (head w) -> att LDS rows [t][c] ----
#pragma unroll
    for (int qt = 0; qt < 4; ++qt)
#pragma unroll
        for (int dt = 0; dt < 2; ++dt) {
            f16x4 ov;
#pragma unroll
            for (int i = 0; i < 4; ++i) ov[i] = (f16)(oT[dt][qt][i] * rq[qt]);
            *((f16x4*)(xlds + (qt * 16 + l15) * XP + w * 32 + dt * 16 + lg * 4)) = ov;
        }

    // force proj weights resident (their loads hid under the whole attention phase)
#pragma unroll
    for (int nt = 0; nt < 2; ++nt) {
#pragma unroll
        for (int ks = 0; ks < 6; ++ks) KEEP(wpf[nt][ks]);
        KEEP(bv[nt]);
    }
    __syncthreads();   // all heads' att visible

    // ---- proj: wave w -> out channels w*32 .. w*32+31 (weights pinned) ----
#pragma unroll
    for (int qt = 0; qt < 4; ++qt) {
        f16x8 af[6];
#pragma unroll
        for (int ks = 0; ks < 6; ++ks)
            af[ks] = *((const f16x8*)(xlds + (qt * 16 + l15) * XP + ks * 32 + lg * 8));
        const int t = qt * 16 + l15;
        const int gy = wy * 8 + (t >> 3), gx = wx * 8 + (t & 7);
        float* orow = out + ((size_t)((b * HDIM + gy) * WDIM + gx)) * C_ + w * 32;
#pragma unroll
        for (int nt = 0; nt < 2; ++nt) {
            f32x4 acc = {0.f, 0.f, 0.f, 0.f};
#pragma unroll
            for (int ks = 0; ks < 6; ++ks)
                acc = __builtin_amdgcn_mfma_f32_16x16x32_f16(wpf[nt][ks], af[ks], acc, 0, 0, 0);
            acc += bv[nt];
            *((f32x4*)(orow + nt * 16 + lg * 4)) = acc;
        }
    }
}

extern "C" void kernel_launch(void* const* d_in, const int* in_sizes, int n_in,
                              void* d_out, int out_size, void* d_ws, size_t ws_size,
                              hipStream_t stream) {
    const float* x      = (const float*)d_in[0];
    const float* qkv_w  = (const float*)d_in[1];
    const float* proj_w = (const float*)d_in[2];
    const float* proj_b = (const float*)d_in[3];
    const float* rpb    = (const float*)d_in[4];
    float* out = (float*)d_out;
    char* ws = (char*)d_ws;
    f16* wqp     = (f16*)(ws + OFF_WQ);
    f16* wpp     = (f16*)(ws + OFF_WP);
    float* biasp = (float*)(ws + OFF_BIAS);

    prep_kernel<<<96, 256, 0, stream>>>(qkv_w, proj_w, rpb, wqp, wpp, biasp);
    fused_kernel<<<4096, 384, 0, stream>>>(x, wqp, wpp, proj_b, biasp, out);
}